// Round 1
// baseline (1368.113 us; speedup 1.0000x reference)
//
#include <hip/hip_runtime.h>

#define BATCH 4096
#define FEAT 41920
#define HACC 256
#define H1 32
#define H2 32

// ---------------------------------------------------------------------------
// Transpose W [HACC x FEAT] row-major -> WT [FEAT x HACC] row-major,
// LDS-tiled so both global read and write are coalesced.
// grid: (FEAT/32, HACC/32), block: (32, 8)
// ---------------------------------------------------------------------------
__global__ __launch_bounds__(256) void transpose_kernel(
    const float* __restrict__ W, float* __restrict__ WT)
{
    __shared__ float tile[32][33];              // +1 pad: conflict-free
    const int fBase = blockIdx.x * 32;
    const int hBase = blockIdx.y * 32;
    const int tx = threadIdx.x;                 // 0..31
    const int ty = threadIdx.y;                 // 0..7

    #pragma unroll
    for (int i = 0; i < 32; i += 8) {
        // read coalesced along F
        tile[ty + i][tx] = W[(size_t)(hBase + ty + i) * FEAT + fBase + tx];
    }
    __syncthreads();
    #pragma unroll
    for (int i = 0; i < 32; i += 8) {
        // write coalesced along H:  WT[f][h] = W[h][f] = tile[tx][ty+i] with f=fBase+ty+i, h=hBase+tx
        WT[(size_t)(fBase + ty + i) * HACC + hBase + tx] = tile[tx][ty + i];
    }
}

// ---------------------------------------------------------------------------
// Fused NNUE forward: one 256-thread block per batch row.
//   Phase A: float4 scan of dense white/black features -> LDS index lists
//   Phase B: sparse accumulate (coalesced 1KB column reads if TRANSPOSED)
//   Phase C: stm blend + clip + tiny MLP tail, all in LDS
// TRANSPOSED: Wx points to [FEAT x HACC] layout; else original [HACC x FEAT].
// ---------------------------------------------------------------------------
template <bool TRANSPOSED>
__global__ __launch_bounds__(256) void nnue_fwd_kernel(
    const float* __restrict__ wfeat, const float* __restrict__ bfeat,
    const float* __restrict__ stm,
    const float* __restrict__ Ww, const float* __restrict__ bw,
    const float* __restrict__ Wb, const float* __restrict__ bb,
    const float* __restrict__ W1, const float* __restrict__ b1,
    const float* __restrict__ W2, const float* __restrict__ b2,
    const float* __restrict__ Wo, const float* __restrict__ bo,
    float* __restrict__ out)
{
    const int row = blockIdx.x;
    const int tid = threadIdx.x;

    __shared__ int   idxW[64], idxB[64];
    __shared__ int   cntW, cntB;
    __shared__ float acc[2 * HACC];
    __shared__ float red[256];
    __shared__ float h1c[H1];
    __shared__ float h2c[H2];

    if (tid == 0) { cntW = 0; cntB = 0; }
    __syncthreads();

    // ---- Phase A: scan (the mandatory 1.37 GB HBM read, float4-vectorized)
    const float4* wf4 = (const float4*)(wfeat + (size_t)row * FEAT);
    const float4* bf4 = (const float4*)(bfeat + (size_t)row * FEAT);
    const int F4 = FEAT / 4;  // 10480
    for (int i = tid; i < F4; i += 256) {
        float4 v = wf4[i];
        if (v.x != 0.f || v.y != 0.f || v.z != 0.f || v.w != 0.f) {
            if (v.x != 0.f) { int p = atomicAdd(&cntW, 1); if (p < 64) idxW[p] = 4 * i + 0; }
            if (v.y != 0.f) { int p = atomicAdd(&cntW, 1); if (p < 64) idxW[p] = 4 * i + 1; }
            if (v.z != 0.f) { int p = atomicAdd(&cntW, 1); if (p < 64) idxW[p] = 4 * i + 2; }
            if (v.w != 0.f) { int p = atomicAdd(&cntW, 1); if (p < 64) idxW[p] = 4 * i + 3; }
        }
        float4 u = bf4[i];
        if (u.x != 0.f || u.y != 0.f || u.z != 0.f || u.w != 0.f) {
            if (u.x != 0.f) { int p = atomicAdd(&cntB, 1); if (p < 64) idxB[p] = 4 * i + 0; }
            if (u.y != 0.f) { int p = atomicAdd(&cntB, 1); if (p < 64) idxB[p] = 4 * i + 1; }
            if (u.z != 0.f) { int p = atomicAdd(&cntB, 1); if (p < 64) idxB[p] = 4 * i + 2; }
            if (u.w != 0.f) { int p = atomicAdd(&cntB, 1); if (p < 64) idxB[p] = 4 * i + 3; }
        }
    }
    __syncthreads();

    const int nw = min(cntW, 64);
    const int nb = min(cntB, 64);

    // ---- Phase B: sparse accumulate; thread tid owns accumulator element tid
    float accW = bw[tid];
    float accB = bb[tid];
    if (TRANSPOSED) {
        for (int i = 0; i < nw; ++i) accW += Ww[(size_t)idxW[i] * HACC + tid];  // coalesced 1KB
        for (int i = 0; i < nb; ++i) accB += Wb[(size_t)idxB[i] * HACC + tid];
    } else {
        for (int i = 0; i < nw; ++i) accW += Ww[(size_t)tid * FEAT + idxW[i]];
        for (int i = 0; i < nb; ++i) accB += Wb[(size_t)tid * FEAT + idxB[i]];
    }

    // ---- stm blend (matches reference: blend raw halves, then clip)
    const float s = stm[row];
    const float a0 = (1.f - s) * accW + s * accB;
    const float a1 = (1.f - s) * accB + s * accW;
    acc[tid]        = fminf(fmaxf(a0, 0.f), 1.f);
    acc[HACC + tid] = fminf(fmaxf(a1, 0.f), 1.f);
    __syncthreads();

    // ---- Phase C: tail MLP
    // h1: 32 outputs x 512 inputs; 8 threads per output, 64 elements each
    {
        const int j = tid >> 3;       // output 0..31
        const int p = tid & 7;        // partial 0..7
        const float* w1row = W1 + (size_t)j * (2 * HACC) + p * 64;
        const float* accp  = acc + p * 64;
        float partial = 0.f;
        #pragma unroll 8
        for (int k = 0; k < 64; ++k) partial += accp[k] * w1row[k];
        red[tid] = partial;
    }
    __syncthreads();
    if ((tid & 7) == 0) {
        const int j = tid >> 3;
        float h = b1[j];
        #pragma unroll
        for (int q = 0; q < 8; ++q) h += red[(j << 3) + q];
        h1c[j] = fminf(fmaxf(h, 0.f), 1.f);
    }
    __syncthreads();
    // h2: 32 outputs x 32 inputs
    if (tid < H2) {
        float h = b2[tid];
        const float* w2row = W2 + (size_t)tid * H1;
        #pragma unroll
        for (int k = 0; k < H1; ++k) h += h1c[k] * w2row[k];
        h2c[tid] = fminf(fmaxf(h, 0.f), 1.f);
    }
    __syncthreads();
    // out: 1 x 32
    if (tid == 0) {
        float o = bo[0];
        #pragma unroll
        for (int k = 0; k < H2; ++k) o += h2c[k] * Wo[k];
        out[row] = o;
    }
}

extern "C" void kernel_launch(void* const* d_in, const int* in_sizes, int n_in,
                              void* d_out, int out_size, void* d_ws, size_t ws_size,
                              hipStream_t stream)
{
    const float* wfeat = (const float*)d_in[0];
    const float* bfeat = (const float*)d_in[1];
    const float* stm   = (const float*)d_in[2];
    const float* Ww    = (const float*)d_in[3];
    const float* bw    = (const float*)d_in[4];
    const float* Wb    = (const float*)d_in[5];
    const float* bb    = (const float*)d_in[6];
    const float* W1    = (const float*)d_in[7];
    const float* b1    = (const float*)d_in[8];
    const float* W2    = (const float*)d_in[9];
    const float* b2    = (const float*)d_in[10];
    const float* Wo    = (const float*)d_in[11];
    const float* bo    = (const float*)d_in[12];
    float* out = (float*)d_out;

    const size_t tsize = (size_t)FEAT * HACC * sizeof(float);  // ~42.9 MB per side

    if (ws_size >= 2 * tsize) {
        float* WwT = (float*)d_ws;
        float* WbT = WwT + (size_t)FEAT * HACC;
        dim3 tgrid(FEAT / 32, HACC / 32);
        dim3 tblk(32, 8);
        transpose_kernel<<<tgrid, tblk, 0, stream>>>(Ww, WwT);
        transpose_kernel<<<tgrid, tblk, 0, stream>>>(Wb, WbT);
        nnue_fwd_kernel<true><<<BATCH, 256, 0, stream>>>(
            wfeat, bfeat, stm, WwT, bw, WbT, bb, W1, b1, W2, b2, Wo, bo, out);
    } else {
        nnue_fwd_kernel<false><<<BATCH, 256, 0, stream>>>(
            wfeat, bfeat, stm, Ww, bw, Wb, bb, W1, b1, W2, b2, Wo, bo, out);
    }
}

// Round 4
// 1328.643 us; speedup vs baseline: 1.0297x; 1.0297x over previous
//
#include <hip/hip_runtime.h>

#define BATCH 4096
#define FEAT 41920
#define HACC 256
#define H1 32
#define H2 32

typedef unsigned int u32x4 __attribute__((ext_vector_type(4)));  // native vec: OK for nontemporal builtins

// ---------------------------------------------------------------------------
// Transpose W [HACC x FEAT] row-major -> WT [FEAT x HACC] row-major,
// LDS-tiled so both global read and write are coalesced.
// grid: (FEAT/32, HACC/32), block: (32, 8)
// ---------------------------------------------------------------------------
__global__ __launch_bounds__(256) void transpose_kernel(
    const float* __restrict__ W, float* __restrict__ WT)
{
    __shared__ float tile[32][33];              // +1 pad: conflict-free
    const int fBase = blockIdx.x * 32;
    const int hBase = blockIdx.y * 32;
    const int tx = threadIdx.x;                 // 0..31
    const int ty = threadIdx.y;                 // 0..7

    #pragma unroll
    for (int i = 0; i < 32; i += 8) {
        tile[ty + i][tx] = W[(size_t)(hBase + ty + i) * FEAT + fBase + tx];
    }
    __syncthreads();
    #pragma unroll
    for (int i = 0; i < 32; i += 8) {
        WT[(size_t)(fBase + ty + i) * HACC + hBase + tx] = tile[tx][ty + i];
    }
}

// ---------------------------------------------------------------------------
// Fused NNUE forward: one 256-thread block per batch row.
//   Phase A: u32x4 nontemporal scan -> LDS index lists (branch-free common path)
//   Phase B: sparse accumulate from transposed weights (coalesced 1KB reads)
//   Phase C: stm blend + clip + tiny MLP tail, all in LDS
// ---------------------------------------------------------------------------
__global__ __launch_bounds__(256) void nnue_fwd_kernel(
    const float* __restrict__ wfeat, const float* __restrict__ bfeat,
    const float* __restrict__ stm,
    const float* __restrict__ WwT, const float* __restrict__ bw,
    const float* __restrict__ WbT, const float* __restrict__ bb,
    const float* __restrict__ W1, const float* __restrict__ b1,
    const float* __restrict__ W2, const float* __restrict__ b2,
    const float* __restrict__ Wo, const float* __restrict__ bo,
    float* __restrict__ out)
{
    const int row = blockIdx.x;
    const int tid = threadIdx.x;

    __shared__ int   idxW[64], idxB[64];
    __shared__ int   cntW, cntB;
    __shared__ float acc[2 * HACC];
    __shared__ float red[256];
    __shared__ float h1c[H1];
    __shared__ float h2c[H2];

    if (tid == 0) { cntW = 0; cntB = 0; }
    __syncthreads();

    // ---- Phase A: scan.  Features are 0.0f/1.0f; integer OR detects nonzero.
    // Common path (~80% of wave-iterations): 2 nt-loads + 6 v_or + 2 cmp + 2
    // uniform branches, no divergence.  nt keeps the 86MB weight table in L3.
    const u32x4* wf4 = (const u32x4*)(wfeat + (size_t)row * FEAT);
    const u32x4* bf4 = (const u32x4*)(bfeat + (size_t)row * FEAT);
    const int F4 = FEAT / 4;  // 10480
    for (int i = tid; i < F4; i += 256) {
        u32x4 v = __builtin_nontemporal_load(&wf4[i]);
        u32x4 u = __builtin_nontemporal_load(&bf4[i]);
        const unsigned nzw = v.x | v.y | v.z | v.w;
        const unsigned nzb = u.x | u.y | u.z | u.w;
        if (__any(nzw != 0u)) {
            if (nzw) {
                if (v.x) { int p = atomicAdd(&cntW, 1); if (p < 64) idxW[p] = 4 * i + 0; }
                if (v.y) { int p = atomicAdd(&cntW, 1); if (p < 64) idxW[p] = 4 * i + 1; }
                if (v.z) { int p = atomicAdd(&cntW, 1); if (p < 64) idxW[p] = 4 * i + 2; }
                if (v.w) { int p = atomicAdd(&cntW, 1); if (p < 64) idxW[p] = 4 * i + 3; }
            }
        }
        if (__any(nzb != 0u)) {
            if (nzb) {
                if (u.x) { int p = atomicAdd(&cntB, 1); if (p < 64) idxB[p] = 4 * i + 0; }
                if (u.y) { int p = atomicAdd(&cntB, 1); if (p < 64) idxB[p] = 4 * i + 1; }
                if (u.z) { int p = atomicAdd(&cntB, 1); if (p < 64) idxB[p] = 4 * i + 2; }
                if (u.w) { int p = atomicAdd(&cntB, 1); if (p < 64) idxB[p] = 4 * i + 3; }
            }
        }
    }
    __syncthreads();

    const int nw = min(cntW, 64);
    const int nb = min(cntB, 64);

    // ---- Phase B: sparse accumulate; thread tid owns accumulator element tid.
    // Each index -> contiguous 1KB row of WT, 256B per wave, fully coalesced.
    float accW = bw[tid];
    float accB = bb[tid];
    for (int i = 0; i < nw; ++i) accW += WwT[(size_t)idxW[i] * HACC + tid];
    for (int i = 0; i < nb; ++i) accB += WbT[(size_t)idxB[i] * HACC + tid];

    // ---- stm blend (matches reference: blend raw halves, then clip)
    const float s = stm[row];
    const float a0 = (1.f - s) * accW + s * accB;
    const float a1 = (1.f - s) * accB + s * accW;
    acc[tid]        = fminf(fmaxf(a0, 0.f), 1.f);
    acc[HACC + tid] = fminf(fmaxf(a1, 0.f), 1.f);
    __syncthreads();

    // ---- Phase C: tail MLP
    // h1: 32 outputs x 512 inputs; 8 threads per output, 64 elements each
    {
        const int j = tid >> 3;       // output 0..31
        const int p = tid & 7;        // partial 0..7
        const float* w1row = W1 + (size_t)j * (2 * HACC) + p * 64;
        const float* accp  = acc + p * 64;
        float partial = 0.f;
        #pragma unroll 8
        for (int k = 0; k < 64; ++k) partial += accp[k] * w1row[k];
        red[tid] = partial;
    }
    __syncthreads();
    if ((tid & 7) == 0) {
        const int j = tid >> 3;
        float h = b1[j];
        #pragma unroll
        for (int q = 0; q < 8; ++q) h += red[(j << 3) + q];
        h1c[j] = fminf(fmaxf(h, 0.f), 1.f);
    }
    __syncthreads();
    // h2: 32 outputs x 32 inputs
    if (tid < H2) {
        float h = b2[tid];
        const float* w2row = W2 + (size_t)tid * H1;
        #pragma unroll
        for (int k = 0; k < H1; ++k) h += h1c[k] * w2row[k];
        h2c[tid] = fminf(fmaxf(h, 0.f), 1.f);
    }
    __syncthreads();
    // out: 1 x 32
    if (tid == 0) {
        float o = bo[0];
        #pragma unroll
        for (int k = 0; k < H2; ++k) o += h2c[k] * Wo[k];
        out[row] = o;
    }
}

extern "C" void kernel_launch(void* const* d_in, const int* in_sizes, int n_in,
                              void* d_out, int out_size, void* d_ws, size_t ws_size,
                              hipStream_t stream)
{
    const float* wfeat = (const float*)d_in[0];
    const float* bfeat = (const float*)d_in[1];
    const float* stm   = (const float*)d_in[2];
    const float* Ww    = (const float*)d_in[3];
    const float* bw    = (const float*)d_in[4];
    const float* Wb    = (const float*)d_in[5];
    const float* bb    = (const float*)d_in[6];
    const float* W1    = (const float*)d_in[7];
    const float* b1    = (const float*)d_in[8];
    const float* W2    = (const float*)d_in[9];
    const float* b2    = (const float*)d_in[10];
    const float* Wo    = (const float*)d_in[11];
    const float* bo    = (const float*)d_in[12];
    float* out = (float*)d_out;

    float* WwT = (float*)d_ws;
    float* WbT = WwT + (size_t)FEAT * HACC;
    dim3 tgrid(FEAT / 32, HACC / 32);
    dim3 tblk(32, 8);
    transpose_kernel<<<tgrid, tblk, 0, stream>>>(Ww, WwT);
    transpose_kernel<<<tgrid, tblk, 0, stream>>>(Wb, WbT);
    nnue_fwd_kernel<<<BATCH, 256, 0, stream>>>(
        wfeat, bfeat, stm, WwT, bw, WbT, bb, W1, b1, W2, b2, Wo, bo, out);
}